// Round 15
// baseline (4347.911 us; speedup 1.0000x reference)
//
#include <hip/hip_runtime.h>
#include <hip/hip_bf16.h>
#include <math.h>

typedef __attribute__((ext_vector_type(8))) short bfrag;   // 8 bf16 (4 VGPRs)
typedef __attribute__((ext_vector_type(4))) float f32x4;

static constexpr int Dm = 1024, Hh = 16, HD = 64, Ll = 12, Tt = 1024, Bb = 4;
static constexpr int Vv = 50257, Mrows = 4096;
static constexpr int PLD = 200;   // partial-LSE leading dim (197 used)

__device__ inline unsigned short f2bf(float f) {  // RNE f32->bf16
    unsigned u = __float_as_uint(f);
    u += 0x7fffu + ((u >> 16) & 1u);
    return (unsigned short)(u >> 16);
}
__device__ inline float bf2f(unsigned short s) {
    return __uint_as_float(((unsigned)s) << 16);
}

__device__ inline void gload16(const unsigned short* g, unsigned short* l) {
    __builtin_amdgcn_global_load_lds(
        (const __attribute__((address_space(1))) void*)g,
        (__attribute__((address_space(3))) void*)l, 16, 0, 0);
}

// ---------------------------------------------------------------- embed (f32)
__global__ __launch_bounds__(256)
void embed_kernel(float* __restrict__ x, const float* __restrict__ wte,
                  const float* __restrict__ wpe, const int* __restrict__ idx) {
    int row = blockIdx.x;
    int t = row & (Tt - 1);
    int id = idx[row];
    int c = threadIdx.x * 4;
    float4 a = *reinterpret_cast<const float4*>(&wte[(size_t)id * Dm + c]);
    float4 p = *reinterpret_cast<const float4*>(&wpe[(size_t)t * Dm + c]);
    float4 o;
    o.x = a.x + p.x; o.y = a.y + p.y; o.z = a.z + p.z; o.w = a.w + p.w;
    *reinterpret_cast<float4*>(&x[(size_t)row * Dm + c]) = o;
}

// ---------------------------------------------------------------- layernorm
__global__ __launch_bounds__(256)
void ln_kernel(unsigned short* __restrict__ y, const float* __restrict__ x,
               const float* __restrict__ w, const float* __restrict__ b) {
    int row = blockIdx.x;
    int tid = threadIdx.x;
    int lane = tid & 63, wv = tid >> 6;
    const float* xr = x + (size_t)row * Dm;
    float4 v = *reinterpret_cast<const float4*>(&xr[tid * 4]);
    float s1 = v.x + v.y + v.z + v.w;
    float s2 = v.x * v.x + v.y * v.y + v.z * v.z + v.w * v.w;
#pragma unroll
    for (int off = 1; off < 64; off <<= 1) {
        s1 += __shfl_xor(s1, off);
        s2 += __shfl_xor(s2, off);
    }
    __shared__ float r1[4], r2[4];
    if (lane == 0) { r1[wv] = s1; r2[wv] = s2; }
    __syncthreads();
    s1 = r1[0] + r1[1] + r1[2] + r1[3];
    s2 = r2[0] + r2[1] + r2[2] + r2[3];
    float mean = s1 * (1.0f / Dm);
    float var = s2 * (1.0f / Dm) - mean * mean;
    float rstd = rsqrtf(var + 1e-5f);
    float4 wvv = *reinterpret_cast<const float4*>(&w[tid * 4]);
    float4 bv = *reinterpret_cast<const float4*>(&b[tid * 4]);
    ushort4 o;
    o.x = f2bf((v.x - mean) * rstd * wvv.x + bv.x);
    o.y = f2bf((v.y - mean) * rstd * wvv.y + bv.y);
    o.z = f2bf((v.z - mean) * rstd * wvv.z + bv.z);
    o.w = f2bf((v.w - mean) * rstd * wvv.w + bv.w);
    *reinterpret_cast<ushort4*>(&y[(size_t)row * Dm + tid * 4]) = o;
}

// ------------------------------------------------- fused per-layer weight transpose
__global__ __launch_bounds__(256)
void transpose_layer(const float* __restrict__ qw, const float* __restrict__ ow,
                     const float* __restrict__ uw, const float* __restrict__ dw,
                     unsigned short* __restrict__ wTq, unsigned short* __restrict__ wTo,
                     unsigned short* __restrict__ wTu, unsigned short* __restrict__ wTd) {
    __shared__ float t[32][33];
    int tb = blockIdx.x;
    const float* src; unsigned short* dst; int K, N, nx, base;
    if (tb < 3072)      { src = qw; dst = wTq; K = 1024; N = 3072; nx = 96;  base = 0; }
    else if (tb < 4096) { src = ow; dst = wTo; K = 1024; N = 1024; nx = 32;  base = 3072; }
    else if (tb < 8192) { src = uw; dst = wTu; K = 1024; N = 4096; nx = 128; base = 4096; }
    else                { src = dw; dst = wTd; K = 4096; N = 1024; nx = 32;  base = 8192; }
    int tt = tb - base;
    int n0 = (tt % nx) * 32, k0 = (tt / nx) * 32;
    int tid = threadIdx.x;
    int r = tid >> 3, c4 = (tid & 7) * 4;
    float4 v = *reinterpret_cast<const float4*>(&src[(size_t)(k0 + r) * N + n0 + c4]);
    t[r][c4] = v.x; t[r][c4 + 1] = v.y; t[r][c4 + 2] = v.z; t[r][c4 + 3] = v.w;
    __syncthreads();
    int nr = tid >> 3, kc = (tid & 7) * 4;
    ushort4 o;
    o.x = f2bf(t[kc][nr]);
    o.y = f2bf(t[kc + 1][nr]);
    o.z = f2bf(t[kc + 2][nr]);
    o.w = f2bf(t[kc + 3][nr]);
    *reinterpret_cast<ushort4*>(&dst[(size_t)(n0 + nr) * K + k0 + kc]) = o;
}

// ------------------------------------------------- f32 rows -> bf16 rows
__global__ __launch_bounds__(128)
void cvt_rows(unsigned short* __restrict__ dst, const float* __restrict__ src) {
    int row = blockIdx.x;
    int t = threadIdx.x;
    const float* s = src + (size_t)row * Dm + t * 8;
    float4 f0 = *reinterpret_cast<const float4*>(s);
    float4 f1 = *reinterpret_cast<const float4*>(s + 4);
    ushort4 o0, o1;
    o0.x = f2bf(f0.x); o0.y = f2bf(f0.y); o0.z = f2bf(f0.z); o0.w = f2bf(f0.w);
    o1.x = f2bf(f1.x); o1.y = f2bf(f1.y); o1.z = f2bf(f1.z); o1.w = f2bf(f1.w);
    unsigned short* d = dst + (size_t)row * Dm + t * 8;
    *reinterpret_cast<ushort4*>(d) = o0;
    *reinterpret_cast<ushort4*>(d + 4) = o1;
}

// ================================================================ 256x256 8-phase GEMM (lm_head)
// 512 thr = 8 waves (2M x 4N), BK=64, 2 K-tiles/iter, half-tile slot ring,
// counted vmcnt(4). EPI 4: C f32 nontemporal + fused LSE partials.
template<int EPI, int GN>
__global__ __launch_bounds__(512, 1)
void gemm256p8(const unsigned short* __restrict__ A, const unsigned short* __restrict__ B,
               const float* __restrict__ bias, void* __restrict__ Cp,
               int Nv, int K, int ldc, int ncol,
               float* __restrict__ pm_out, float* __restrict__ ps_out) {
    __shared__ unsigned short AL[2][2][8192];   // [dbuf][half][128*64]
    __shared__ unsigned short BL[2][2][8192];
    const int tid = threadIdx.x;
    const int lane = tid & 63, w = tid >> 6;
    const int wr = w >> 2, wc = w & 3;
    const int g = lane >> 4, lr = lane & 15;

    const int gx = gridDim.x;
    const int ny = GN ? ((Nv + 255) >> 8) : (int)gridDim.y;
    int s = blockIdx.y * gx + blockIdx.x;
    int xcd = s & 7, t0b = s >> 3;
    int xblk = t0b % gx, istr = t0b / gx;
    int y = xcd + (istr << 3);
    if (GN && y >= ny) return;
    const int bm = xblk * 256;
    const int bn = y * 256;

    const int srow = tid >> 3;
    const int gsrc = (tid & 7) ^ (srow & 7);
    size_t aofs[2][2], bofs[2][2];
#pragma unroll
    for (int h = 0; h < 2; ++h)
#pragma unroll
        for (int j = 0; j < 2; ++j) {
            int ra = bm + h * 128 + srow + j * 64;
            aofs[h][j] = (size_t)ra * K + gsrc * 8;
            int rb = bn + h * 128 + srow + j * 64;
            if (GN) rb = (rb < Nv) ? rb : (Nv - 1);
            bofs[h][j] = (size_t)rb * K + gsrc * 8;
        }
    const int dst0 = tid * 8, dst1 = tid * 8 + 4096;

    const int nt = K >> 6;
    const int ni = nt >> 1;

    f32x4 acc[8][4];
#pragma unroll
    for (int i = 0; i < 8; ++i)
#pragma unroll
        for (int j = 0; j < 4; ++j)
#pragma unroll
            for (int r = 0; r < 4; ++r) acc[i][j][r] = 0.f;

#define STG_A(d, h, kt) do { \
        gload16(A + aofs[h][0] + ((size_t)(kt) << 6), &AL[d][h][dst0]); \
        gload16(A + aofs[h][1] + ((size_t)(kt) << 6), &AL[d][h][dst1]); } while (0)
#define STG_B(d, h, kt) do { \
        gload16(B + bofs[h][0] + ((size_t)(kt) << 6), &BL[d][h][dst0]); \
        gload16(B + bofs[h][1] + ((size_t)(kt) << 6), &BL[d][h][dst1]); } while (0)

    STG_B(0, 0, 0); STG_B(0, 1, 0);
    STG_A(0, 0, 0); STG_A(0, 1, 0);
    STG_B(1, 0, 1); STG_B(1, 1, 1);
    asm volatile("s_waitcnt vmcnt(0)" ::: "memory");
    asm volatile("s_barrier" ::: "memory");

    const unsigned short* alw[2] = { &AL[0][wr][0], &AL[1][wr][0] };
    const unsigned short* blw[2] = { &BL[0][wc >> 1][0], &BL[1][wc >> 1][0] };
    const int rbB = (wc & 1) * 64;

    bfrag bfr[4][2], afr[2][2];

    for (int i = 0; i < ni; ++i) {
        const int t1 = 2 * i + 1;
        const int tp0 = 2 * i + 2, tp1 = 2 * i + 3;
        const bool pf = (tp0 < nt);
#pragma unroll
        for (int q = 0; q < 4; ++q) {
            if (q == 0) {
#pragma unroll
                for (int n_ = 0; n_ < 4; ++n_)
#pragma unroll
                    for (int ks = 0; ks < 2; ++ks) {
                        int row = rbB + n_ * 16 + lr;
                        int sg = (ks * 4 + g) ^ (row & 7);
                        bfr[n_][ks] = *reinterpret_cast<const bfrag*>(&blw[0][row * 64 + sg * 8]);
                    }
            }
#pragma unroll
            for (int m2 = 0; m2 < 2; ++m2)
#pragma unroll
                for (int ks = 0; ks < 2; ++ks) {
                    int row = q * 32 + m2 * 16 + lr;
                    int sg = (ks * 4 + g) ^ (row & 7);
                    afr[m2][ks] = *reinterpret_cast<const bfrag*>(&alw[0][row * 64 + sg * 8]);
                }
            if (q == 0)      { STG_A(1, 0, t1); }
            else if (q == 1) { STG_A(1, 1, t1); }
            else if (q == 2) { if (pf) STG_B(0, 0, tp0); }
            else             { if (pf) STG_B(0, 1, tp0); }
            asm volatile("s_barrier" ::: "memory");
            __builtin_amdgcn_s_setprio(1);
#pragma unroll
            for (int m2 = 0; m2 < 2; ++m2)
#pragma unroll
                for (int n_ = 0; n_ < 4; ++n_)
#pragma unroll
                    for (int ks = 0; ks < 2; ++ks)
                        acc[q * 2 + m2][n_] = __builtin_amdgcn_mfma_f32_16x16x32_bf16(
                            afr[m2][ks], bfr[n_][ks], acc[q * 2 + m2][n_], 0, 0, 0);
            __builtin_amdgcn_s_setprio(0);
            if (q == 3) {
                if (i + 1 < ni) asm volatile("s_waitcnt vmcnt(4)" ::: "memory");
                else            asm volatile("s_waitcnt vmcnt(0)" ::: "memory");
            }
            asm volatile("s_barrier" ::: "memory");
        }
#pragma unroll
        for (int q = 0; q < 4; ++q) {
            if (q == 0) {
#pragma unroll
                for (int n_ = 0; n_ < 4; ++n_)
#pragma unroll
                    for (int ks = 0; ks < 2; ++ks) {
                        int row = rbB + n_ * 16 + lr;
                        int sg = (ks * 4 + g) ^ (row & 7);
                        bfr[n_][ks] = *reinterpret_cast<const bfrag*>(&blw[1][row * 64 + sg * 8]);
                    }
            }
#pragma unroll
            for (int m2 = 0; m2 < 2; ++m2)
#pragma unroll
                for (int ks = 0; ks < 2; ++ks) {
                    int row = q * 32 + m2 * 16 + lr;
                    int sg = (ks * 4 + g) ^ (row & 7);
                    afr[m2][ks] = *reinterpret_cast<const bfrag*>(&alw[1][row * 64 + sg * 8]);
                }
            if (q == 0)      { if (pf) STG_A(0, 0, tp0); }
            else if (q == 1) { if (pf) STG_A(0, 1, tp0); }
            else if (q == 2) { if (tp1 < nt) STG_B(1, 0, tp1); }
            else             { if (tp1 < nt) STG_B(1, 1, tp1); }
            asm volatile("s_barrier" ::: "memory");
            __builtin_amdgcn_s_setprio(1);
#pragma unroll
            for (int m2 = 0; m2 < 2; ++m2)
#pragma unroll
                for (int n_ = 0; n_ < 4; ++n_)
#pragma unroll
                    for (int ks = 0; ks < 2; ++ks)
                        acc[q * 2 + m2][n_] = __builtin_amdgcn_mfma_f32_16x16x32_bf16(
                            afr[m2][ks], bfr[n_][ks], acc[q * 2 + m2][n_], 0, 0, 0);
            __builtin_amdgcn_s_setprio(0);
            if (q == 3 && i + 1 < ni) asm volatile("s_waitcnt vmcnt(4)" ::: "memory");
            asm volatile("s_barrier" ::: "memory");
        }
    }
#undef STG_A
#undef STG_B

    float* Cf = (float*)Cp;
    {
        // fused logits store + per-row LSE partial over this block's 256 cols
        __syncthreads();
        float* lm = (float*)&AL[0][0][0];      // [256][4] row-max partials
        float* lsd = lm + 1024;                // [256][4] row-sumexp partials
        float bi4[4];
        int colv[4];
#pragma unroll
        for (int n_ = 0; n_ < 4; ++n_) {
            colv[n_] = bn + wc * 64 + n_ * 16 + lr;
            bi4[n_] = (colv[n_] < Nv) ? bias[ncol + colv[n_]] : 0.f;
        }
#pragma unroll
        for (int mi = 0; mi < 8; ++mi) {
#pragma unroll
            for (int r = 0; r < 4; ++r) {
                int row = bm + wr * 128 + mi * 16 + g * 4 + r;
                float vv[4];
                float ml = -3.0e38f, sl = 0.f;
#pragma unroll
                for (int n_ = 0; n_ < 4; ++n_) {
                    float v = acc[mi][n_][r] + bi4[n_];
                    vv[n_] = v;
                    if (colv[n_] < Nv) ml = fmaxf(ml, v);
                }
#pragma unroll
                for (int n_ = 0; n_ < 4; ++n_) {
                    if (colv[n_] < Nv) {
                        sl += __expf(vv[n_] - ml);
                        __builtin_nontemporal_store(
                            vv[n_], &Cf[(size_t)row * ldc + ncol + colv[n_]]);
                    }
                }
#pragma unroll
                for (int off = 1; off < 16; off <<= 1) {
                    float om = __shfl_xor(ml, off);
                    float os = __shfl_xor(sl, off);
                    float nm = fmaxf(ml, om);
                    sl = sl * __expf(ml - nm) + os * __expf(om - nm);
                    ml = nm;
                }
                if (lr == 0) {
                    int lrow = wr * 128 + mi * 16 + g * 4 + r;
                    lm[lrow * 4 + wc] = ml;
                    lsd[lrow * 4 + wc] = sl;
                }
            }
        }
        __syncthreads();
        if (tid < 256) {
            float m0 = lm[tid * 4 + 0], m1 = lm[tid * 4 + 1];
            float m2 = lm[tid * 4 + 2], m3 = lm[tid * 4 + 3];
            float M = fmaxf(fmaxf(m0, m1), fmaxf(m2, m3));
            float S = lsd[tid * 4 + 0] * __expf(m0 - M) + lsd[tid * 4 + 1] * __expf(m1 - M)
                    + lsd[tid * 4 + 2] * __expf(m2 - M) + lsd[tid * 4 + 3] * __expf(m3 - M);
            int row = bm + tid;
            int bno = bn >> 8;
            pm_out[(size_t)row * PLD + bno] = M;
            ps_out[(size_t)row * PLD + bno] = S;
        }
    }
}

// ================================================================ 128x128 pipelined GEMM
// 256 thr = 4 waves (2x2), per-wave 64x64. 64 KB LDS -> 2 blocks/CU.
// Merged phase + counted vmcnt ring. Stripe-affinity XCD mapping (gridDim.y % 8 == 0).
// EPI 0: bf16+bias. 1: bf16 = gelu(acc+bias). 2: f32 = R+acc+bias.
template<int EPI>
__global__ __launch_bounds__(256, 2)
void gemm128p(const unsigned short* __restrict__ A, const unsigned short* __restrict__ B,
              const float* __restrict__ bias, const float* __restrict__ R,
              void* __restrict__ Cp, int K, int ldc) {
    __shared__ unsigned short As[4][128 * 32];
    __shared__ unsigned short Bs[4][128 * 32];
    const int tid = threadIdx.x;
    const int lane = tid & 63, w = tid >> 6;
    const int wr = w >> 1, wc = w & 1;
    const int g = lane >> 4, lr = lane & 15;
    const int slotk = (lr >> 1) & 3;

    const int gx = gridDim.x;
    int s = blockIdx.y * gx + blockIdx.x;
    int xcd = s & 7, t0 = s >> 3;
    int xblk = t0 % gx, istr = t0 / gx;
    int y = xcd + (istr << 3);
    const int bm = xblk * 128;
    const int bn = y * 128;

    const int srow = lane >> 2;
    const int gsrc = (lane & 3) ^ ((lane >> 3) & 3);
    const int rA0 = (w * 2 + 0) * 16 + srow;
    const int rA1 = (w * 2 + 1) * 16 + srow;
    const size_t aoff0 = (size_t)(bm + rA0) * K + gsrc * 8;
    const size_t aoff1 = (size_t)(bm + rA1) * K + gsrc * 8;
    const size_t boff0 = (size_t)(bn + rA0) * K + gsrc * 8;
    const size_t boff1 = (size_t)(bn + rA1) * K + gsrc * 8;
    unsigned short* lA0 = &As[0][(w * 2 + 0) * 512];
    unsigned short* lA1 = &As[0][(w * 2 + 1) * 512];
    unsigned short* lB0 = &Bs[0][(w * 2 + 0) * 512];
    unsigned short* lB1 = &Bs[0][(w * 2 + 1) * 512];

    const int nt = K >> 5;

    f32x4 acc[4][4];
#pragma unroll
    for (int i = 0; i < 4; ++i)
#pragma unroll
        for (int j = 0; j < 4; ++j)
#pragma unroll
            for (int r = 0; r < 4; ++r) acc[i][j][r] = 0.f;

#pragma unroll
    for (int tp = 0; tp < 3; ++tp) {
        const int kp = tp << 5;
        gload16(A + aoff0 + kp, lA0 + tp * 4096);
        gload16(B + boff0 + kp, lB0 + tp * 4096);
        gload16(A + aoff1 + kp, lA1 + tp * 4096);
        gload16(B + boff1 + kp, lB1 + tp * 4096);
    }
    asm volatile("s_waitcnt vmcnt(8)" ::: "memory");
    asm volatile("s_barrier" ::: "memory");

    for (int t = 0; t < nt; ++t) {
        const int bt = t & 3;
        const unsigned short* as = As[bt];
        const unsigned short* bs = Bs[bt];
        const int pf = t + 3;
        const int kp = pf << 5;
        const int so = (pf & 3) * 4096;

        bfrag af[4], bfr[4];
#pragma unroll
        for (int i = 0; i < 4; ++i) {
            int ra = wr * 64 + i * 16 + lr;
            af[i] = *reinterpret_cast<const bfrag*>(&as[ra * 32 + ((g ^ slotk) * 8)]);
            int rb = wc * 64 + i * 16 + lr;
            bfr[i] = *reinterpret_cast<const bfrag*>(&bs[rb * 32 + ((g ^ slotk) * 8)]);
        }
        if (pf < nt) {
            gload16(A + aoff0 + kp, lA0 + so);
            gload16(B + boff0 + kp, lB0 + so);
            gload16(A + aoff1 + kp, lA1 + so);
            gload16(B + boff1 + kp, lB1 + so);
        }
        __builtin_amdgcn_s_setprio(1);
#pragma unroll
        for (int mi = 0; mi < 4; ++mi)
#pragma unroll
            for (int ni = 0; ni < 4; ++ni)
                acc[mi][ni] = __builtin_amdgcn_mfma_f32_16x16x32_bf16(
                    af[mi], bfr[ni], acc[mi][ni], 0, 0, 0);
        __builtin_amdgcn_s_setprio(0);
        if (t + 3 < nt)      asm volatile("s_waitcnt vmcnt(8)" ::: "memory");
        else if (t + 2 < nt) asm volatile("s_waitcnt vmcnt(4)" ::: "memory");
        else if (t + 1 < nt) asm volatile("s_waitcnt vmcnt(0)" ::: "memory");
        asm volatile("s_barrier" ::: "memory");
    }

    unsigned short* Cb = (unsigned short*)Cp;
    float* Cf = (float*)Cp;
#pragma unroll
    for (int ni = 0; ni < 4; ++ni) {
        int col = bn + wc * 64 + ni * 16 + lr;
        float bi = bias[col];
#pragma unroll
        for (int mi = 0; mi < 4; ++mi) {
            int row0 = bm + wr * 64 + mi * 16 + g * 4;
#pragma unroll
            for (int r = 0; r < 4; ++r) {
                int row = row0 + r;
                float v = acc[mi][ni][r] + bi;
                if (EPI == 0) {
                    Cb[(size_t)row * ldc + col] = f2bf(v);
                } else if (EPI == 1) {
                    v = 0.5f * v * (1.0f + erff(v * 0.70710678118654752f));
                    Cb[(size_t)row * ldc + col] = f2bf(v);
                } else {
                    Cf[(size_t)row * ldc + col] = R[(size_t)row * ldc + col] + v;
                }
            }
        }
    }
}

// ---------------------------------------------------------------- MFMA attention
__global__ __launch_bounds__(256)
void attn_mfma(const unsigned short* __restrict__ qkv, unsigned short* __restrict__ ob) {
    const int bq = blockIdx.x;
    const int h = blockIdx.y;
    const int b = blockIdx.z;
    const int tid = threadIdx.x, lane = tid & 63, w = tid >> 6;
    const int g = lane >> 4, lr = lane & 15;
    const int qg0 = bq * 128 + w * 32;

    __shared__ unsigned short Kt[64 * 72];
    __shared__ unsigned short Vt[64 * 72];
    __shared__ unsigned short Pl[4][32 * 72];
    unsigned short* Plw = Pl[w];

    bfrag aq[2][2];
#pragma unroll
    for (int qs = 0; qs < 2; ++qs)
#pragma unroll
        for (int ks = 0; ks < 2; ++ks) {
            int row = qg0 + qs * 16 + lr;
            aq[qs][ks] = *reinterpret_cast<const bfrag*>(
                &qkv[(size_t)(b * Tt + row) * 3072 + h * 64 + ks * 32 + g * 8]);
        }

    float mrow[2][4], lrow[2][4], osc[2][4];
    f32x4 oacc[2][4];
#pragma unroll
    for (int qs = 0; qs < 2; ++qs)
#pragma unroll
        for (int r = 0; r < 4; ++r) { mrow[qs][r] = -3.0e38f; lrow[qs][r] = 0.f; }
#pragma unroll
    for (int qs = 0; qs < 2; ++qs)
#pragma unroll
        for (int dn = 0; dn < 4; ++dn)
#pragma unroll
            for (int r = 0; r < 4; ++r) oacc[qs][dn][r] = 0.f;

    const int ntile = 2 * bq + 2;
    for (int kt = 0; kt < ntile; ++kt) {
        {
            int row = tid >> 2, seg = tid & 3;
            const unsigned short* sk =
                &qkv[(size_t)(b * Tt + kt * 64 + row) * 3072 + Dm + h * 64 + seg * 16];
            bfrag kv0 = *(const bfrag*)sk;
            bfrag kv1 = *(const bfrag*)(sk + 8);
            *reinterpret_cast<bfrag*>(&Kt[row * 72 + seg * 16]) = kv0;
            *reinterpret_cast<bfrag*>(&Kt[row * 72 + seg * 16 + 8]) = kv1;
            const uint4* sv = reinterpret_cast<const uint4*>(
                &qkv[(size_t)(b * Tt + kt * 64 + row) * 3072 + 2 * Dm + h * 64 + seg * 16]);
            uint4 u0 = sv[0], u1 = sv[1];
            uint4 a, r0, r1;
            a.x = (seg & 1) ? u0.y : u0.x; a.y = (seg & 1) ? u0.z : u0.y;
            a.z = (seg & 1) ? u0.w : u0.z; a.w = (seg & 1) ? u0.x : u0.w;
            r0.x = (seg & 2) ? a.z : a.x; r0.y = (seg & 2) ? a.w : a.y;
            r0.z = (seg & 2) ? a.x : a.z; r0.w = (seg & 2) ? a.y : a.w;
            a.x = (seg & 1) ? u1.y : u1.x; a.y = (seg & 1) ? u1.z : u1.y;
            a.z = (seg & 1) ? u1.w : u1.z; a.w = (seg & 1) ? u1.x : u1.w;
            r1.x = (seg & 2) ? a.z : a.x; r1.y = (seg & 2) ? a.w : a.y;
            r1.z = (seg & 2) ? a.x : a.z; r1.w = (seg & 2) ? a.y : a.w;
            unsigned w0[4] = {r0.x, r0.y, r0.z, r0.w};
            unsigned w1[4] = {r1.x, r1.y, r1.z, r1.w};
#pragma unroll
            for (int i = 0; i < 8; ++i) {
                int j = (i + 2 * seg) & 7;
                unsigned ww = w0[i >> 1];
                unsigned short val = (i & 1) ? (unsigned short)(ww >> 16)
                                             : (unsigned short)(ww & 0xffff);
                Vt[(seg * 16 + j) * 72 + row] = val;
            }
#pragma unroll
            for (int i = 0; i < 8; ++i) {
                int j = (i + 2 * seg) & 7;
                unsigned ww = w1[i >> 1];
                unsigned short val = (i & 1) ? (unsigned short)(ww >> 16)
                                             : (unsigned short)(ww & 0xffff);
                Vt[(seg * 16 + 8 + j) * 72 + row] = val;
            }
        }
        __syncthreads();

        bool active = (kt * 64 <= qg0 + 31);
        if (active) {
            f32x4 s[2][4];
#pragma unroll
            for (int qs = 0; qs < 2; ++qs)
#pragma unroll
                for (int n = 0; n < 4; ++n)
#pragma unroll
                    for (int r = 0; r < 4; ++r) s[qs][n][r] = 0.f;
            bfrag bk[4][2];
#pragma unroll
            for (int n = 0; n < 4; ++n)
#pragma unroll
                for (int ks = 0; ks < 2; ++ks)
                    bk[n][ks] = *reinterpret_cast<const bfrag*>(
                        &Kt[(n * 16 + lr) * 72 + ks * 32 + g * 8]);
#pragma unroll
            for (int qs = 0; qs < 2; ++qs)
#pragma unroll
                for (int n = 0; n < 4; ++n)
#pragma unroll
                    for (int ks = 0; ks < 2; ++ks)
                        s[qs][n] = __builtin_amdgcn_mfma_f32_16x16x32_bf16(
                            aq[qs][ks], bk[n][ks], s[qs][n], 0, 0, 0);

            bool mayMask = (kt * 64 + 63 > qg0);
            float pv[2][4][4];
#pragma unroll
            for (int qs = 0; qs < 2; ++qs) {
#pragma unroll
                for (int r = 0; r < 4; ++r) {
                    int qrow = qg0 + qs * 16 + g * 4 + r;
                    float v[4];
#pragma unroll
                    for (int n = 0; n < 4; ++n) {
                        float sv = s[qs][n][r] * 0.125f;
                        if (mayMask && (kt * 64 + n * 16 + lr > qrow)) sv = -3.0e38f;
                        v[n] = sv;
                    }
                    float tmax = fmaxf(fmaxf(v[0], v[1]), fmaxf(v[2], v[3]));
                    tmax = fmaxf(tmax, __shfl_xor(tmax, 1));
                    tmax = fmaxf(tmax, __shfl_xor(tmax, 2));
                    tmax = fmaxf(tmax, __shfl_xor(tmax, 4));
                    tmax = fmaxf(tmax, __shfl_xor(tmax, 8));
                    float mold = mrow[qs][r];
                    float mnew = fmaxf(mold, tmax);
                    float scl = expf(mold - mnew);
                    float psum = 0.f;
#pragma unroll
                    for (int n = 0; n < 4; ++n) {
                        float p = expf(v[n] - mnew);
                        pv[qs][n][r] = p;
                        psum += p;
                    }
                    psum += __shfl_xor(psum, 1);
                    psum += __shfl_xor(psum, 2);
                    psum += __shfl_xor(psum, 4);
                    psum += __shfl_xor(psum, 8);
                    lrow[qs][r] = lrow[qs][r] * scl + psum;
                    mrow[qs][r] = mnew;
                    osc[qs][r] = scl;
                }
            }
#pragma unroll
            for (int qs = 0; qs < 2; ++qs)
#pragma unroll
                for (int dn = 0; dn < 4; ++dn)
#pragma unroll
                    for (int r = 0; r < 4; ++r) oacc[qs][dn][r] *= osc[qs][r];
#pragma unroll
            for (int qs = 0; qs < 2; ++qs)
#pragma unroll
                for (int n = 0; n < 4; ++n)
#pragma unroll
                    for (int r = 0; r < 4; ++r)
                        Plw[(qs * 16 + g * 4 + r) * 72 + n * 16 + lr] = f2bf(pv[qs][n][r]);
            asm volatile("s_waitcnt lgkmcnt(0)" ::: "memory");
            bfrag ap[2][2], bv[4][2];
#pragma unroll
            for (int qs = 0; qs < 2; ++qs)
#pragma unroll
                for (int ks = 0; ks < 2; ++ks)
                    ap[qs][ks] = *reinterpret_cast<const bfrag*>(
                        &Plw[(qs * 16 + lr) * 72 + ks * 32 + g * 8]);
#pragma unroll
            for (int dn = 0; dn < 4; ++dn)
#pragma unroll
                for (int ks = 0; ks < 2; ++ks)
                    bv[dn][ks] = *reinterpret_cast<const bfrag*>(
                        &Vt[(dn * 16 + lr) * 72 + ks * 32 + g * 8]);
#pragma unroll
            for (int qs = 0; qs < 2; ++qs)
#pragma unroll
                for (int dn = 0; dn < 4; ++dn)
#pragma unroll
                    for (int ks = 0; ks < 2; ++ks)
                        oacc[qs][dn] = __builtin_amdgcn_mfma_f32_16x16x32_bf16(
                            ap[qs][ks], bv[dn][ks], oacc[qs][dn], 0, 0, 0);
        }
        __syncthreads();
    }

#pragma unroll
    for (int qs = 0; qs < 2; ++qs)
#pragma unroll
        for (int r = 0; r < 4; ++r) {
            float rinv = 1.0f / lrow[qs][r];
            int qrow = qg0 + qs * 16 + g * 4 + r;
#pragma unroll
            for (int dn = 0; dn < 4; ++dn)
                ob[(size_t)(b * Tt + qrow) * Dm + h * 64 + dn * 16 + lr] =
                    f2bf(oacc[qs][dn][r] * rinv);
        }
}

// ---------------------------------------------------------------- loss combine
__global__ __launch_bounds__(64)
void loss_combine(float* __restrict__ nll, const float* __restrict__ pm,
                  const float* __restrict__ ps, const float* __restrict__ logits,
                  const int* __restrict__ targets, int nby) {
    const int row = blockIdx.x;
    const int lane = threadIdx.x;
    float m = -3.0e38f, s = 0.f;
    for (int j = lane; j < nby; j += 64) {
        float om = pm[(size_t)row * PLD + j];
        float os = ps[(size_t)row * PLD + j];
        float nm = fmaxf(m, om);
        s = s * __expf(m - nm) + os * __expf(om - nm);
        m = nm;
    }
#pragma unroll
    for (int off = 1; off < 64; off <<= 1) {
        float om = __shfl_xor(m, off);
        float os = __shfl_xor(s, off);
        float nm = fmaxf(m, om);
        s = s * __expf(m - nm) + os * __expf(om - nm);
        m = nm;
    }
    if (lane == 0) {
        float lse = m + __logf(s);
        nll[row] = lse - logits[(size_t)row * Vv + targets[row]];
    }
}

__global__ __launch_bounds__(256)
void loss_reduce_kernel(float* __restrict__ loss, const float* __restrict__ nll) {
    int tid = threadIdx.x;
    __shared__ float red[256];
    float s = 0.f;
    for (int j = tid; j < Mrows; j += 256) s += nll[j];
    red[tid] = s;
    __syncthreads();
    for (int st = 128; st > 0; st >>= 1) {
        if (tid < st) red[tid] += red[tid + st];
        __syncthreads();
    }
    if (tid == 0) *loss = red[0] * (1.0f / Mrows);
}

// ---------------------------------------------------------------- launch
extern "C" void kernel_launch(void* const* d_in, const int* in_sizes, int n_in,
                              void* d_out, int out_size, void* d_ws, size_t ws_size,
                              hipStream_t stream) {
    const int* idx = (const int*)d_in[0];
    const int* targets = (const int*)d_in[1];
    const float* wte = (const float*)d_in[2];
    const float* wpe = (const float*)d_in[3];
    const float* ln1_w = (const float*)d_in[4];
    const float* ln1_b = (const float*)d_in[5];
    const float* qkv_w = (const float*)d_in[6];
    const float* qkv_b = (const float*)d_in[7];
    const float* o_w = (const float*)d_in[8];
    const float* o_b = (const float*)d_in[9];
    const float* ln2_w = (const float*)d_in[10];
    const float* ln2_b = (const float*)d_in[11];
    const float* up_w = (const float*)d_in[12];
    const float* up_b = (const float*)d_in[13];
    const float* down_w = (const float*)d_in[14];
    const float* down_b = (const float*)d_in[15];
    const float* lnf_w = (const float*)d_in[16];
    const float* lnf_b = (const float*)d_in[17];
    const float* lm_b = (const float*)d_in[18];

    float* logits = (float*)d_out;
    char* ws = (char*)d_ws;
    const size_t MB = 1 << 20;
    float* x            = (float*)(ws);                       // 16 MB
    unsigned short* y   = (unsigned short*)(ws + 16 * MB);    // 8 MB
    unsigned short* qkv = (unsigned short*)(ws + 24 * MB);    // 24 MB
    unsigned short* ob  = (unsigned short*)(ws + 48 * MB);    // 8 MB
    unsigned short* up  = (unsigned short*)(ws + 56 * MB);    // 32 MB
    unsigned short* wTq = (unsigned short*)(ws + 88 * MB);    // 6.3 MB
    unsigned short* wTo = (unsigned short*)(ws + 96 * MB);    // 2.1 MB
    unsigned short* wTu = (unsigned short*)(ws + 100 * MB);   // 8.4 MB
    unsigned short* wTd = (unsigned short*)(ws + 112 * MB);   // 8.4 MB
    float* nll          = (float*)(ws + 127 * MB);            // 16 KB
    unsigned short* wbf = (unsigned short*)(ws + 24 * MB);    // lm phase (reuses qkv..)
    float* pmp          = (float*)(ws + 131 * MB);            // 3.3 MB
    float* psp          = (float*)(ws + 136 * MB);            // 3.3 MB

    embed_kernel<<<Mrows, 256, 0, stream>>>(x, wte, wpe, idx);

    for (int l = 0; l < Ll; ++l) {
        ln_kernel<<<Mrows, 256, 0, stream>>>(y, x, ln1_w + l * Dm, ln1_b + l * Dm);
        transpose_layer<<<12288, 256, 0, stream>>>(
            qkv_w + (size_t)l * Dm * 3 * Dm, o_w + (size_t)l * Dm * Dm,
            up_w + (size_t)l * Dm * 4 * Dm, down_w + (size_t)l * 4 * Dm * Dm,
            wTq, wTo, wTu, wTd);
        gemm128p<0><<<dim3(Mrows / 128, 3 * Dm / 128), 256, 0, stream>>>(
            y, wTq, qkv_b + (size_t)l * 3 * Dm, nullptr, qkv, Dm, 3 * Dm);
        attn_mfma<<<dim3(8, Hh, Bb), 256, 0, stream>>>(qkv, ob);
        gemm128p<2><<<dim3(Mrows / 128, Dm / 128), 256, 0, stream>>>(
            ob, wTo, o_b + (size_t)l * Dm, x, x, Dm, Dm);
        ln_kernel<<<Mrows, 256, 0, stream>>>(y, x, ln2_w + l * Dm, ln2_b + l * Dm);
        gemm128p<1><<<dim3(Mrows / 128, 4 * Dm / 128), 256, 0, stream>>>(
            y, wTu, up_b + (size_t)l * 4 * Dm, nullptr, up, Dm, 4 * Dm);
        gemm128p<2><<<dim3(Mrows / 128, Dm / 128), 256, 0, stream>>>(
            up, wTd, down_b + (size_t)l * Dm, x, x, 4 * Dm, Dm);
    }

    ln_kernel<<<Mrows, 256, 0, stream>>>(y, x, lnf_w, lnf_b);

    cvt_rows<<<Vv, 128, 0, stream>>>(wbf, wte);
    const int NBY = (Vv + 255) / 256;         // 197 valid stripes
    const int NBY_PAD = ((NBY + 7) / 8) * 8;  // 200 padded
    gemm256p8<4, 1><<<dim3(Mrows / 256, NBY_PAD), 512, 0, stream>>>(
        y, wbf, lm_b, logits, Vv, Dm, Vv, 0, pmp, psp);

    loss_combine<<<Mrows, 64, 0, stream>>>(nll, pmp, psp, logits, targets, NBY);
    loss_reduce_kernel<<<1, 256, 0, stream>>>(logits + (size_t)Mrows * Vv, nll);
}

// Round 16
// 4295.295 us; speedup vs baseline: 1.0122x; 1.0122x over previous
//
#include <hip/hip_runtime.h>
#include <hip/hip_bf16.h>
#include <math.h>

typedef __attribute__((ext_vector_type(8))) short bfrag;   // 8 bf16 (4 VGPRs)
typedef __attribute__((ext_vector_type(4))) float f32x4;

static constexpr int Dm = 1024, Hh = 16, HD = 64, Ll = 12, Tt = 1024, Bb = 4;
static constexpr int Vv = 50257, Mrows = 4096;
static constexpr int PLD = 200;   // partial-LSE leading dim (197 used)

__device__ inline unsigned short f2bf(float f) {  // RNE f32->bf16
    unsigned u = __float_as_uint(f);
    u += 0x7fffu + ((u >> 16) & 1u);
    return (unsigned short)(u >> 16);
}
__device__ inline float bf2f(unsigned short s) {
    return __uint_as_float(((unsigned)s) << 16);
}

__device__ inline void gload16(const unsigned short* g, unsigned short* l) {
    __builtin_amdgcn_global_load_lds(
        (const __attribute__((address_space(1))) void*)g,
        (__attribute__((address_space(3))) void*)l, 16, 0, 0);
}

// ---------------------------------------------------------------- embed (f32)
__global__ __launch_bounds__(256)
void embed_kernel(float* __restrict__ x, const float* __restrict__ wte,
                  const float* __restrict__ wpe, const int* __restrict__ idx) {
    int row = blockIdx.x;
    int t = row & (Tt - 1);
    int id = idx[row];
    int c = threadIdx.x * 4;
    float4 a = *reinterpret_cast<const float4*>(&wte[(size_t)id * Dm + c]);
    float4 p = *reinterpret_cast<const float4*>(&wpe[(size_t)t * Dm + c]);
    float4 o;
    o.x = a.x + p.x; o.y = a.y + p.y; o.z = a.z + p.z; o.w = a.w + p.w;
    *reinterpret_cast<float4*>(&x[(size_t)row * Dm + c]) = o;
}

// ---------------------------------------------------------------- layernorm
__global__ __launch_bounds__(256)
void ln_kernel(unsigned short* __restrict__ y, const float* __restrict__ x,
               const float* __restrict__ w, const float* __restrict__ b) {
    int row = blockIdx.x;
    int tid = threadIdx.x;
    int lane = tid & 63, wv = tid >> 6;
    const float* xr = x + (size_t)row * Dm;
    float4 v = *reinterpret_cast<const float4*>(&xr[tid * 4]);
    float s1 = v.x + v.y + v.z + v.w;
    float s2 = v.x * v.x + v.y * v.y + v.z * v.z + v.w * v.w;
#pragma unroll
    for (int off = 1; off < 64; off <<= 1) {
        s1 += __shfl_xor(s1, off);
        s2 += __shfl_xor(s2, off);
    }
    __shared__ float r1[4], r2[4];
    if (lane == 0) { r1[wv] = s1; r2[wv] = s2; }
    __syncthreads();
    s1 = r1[0] + r1[1] + r1[2] + r1[3];
    s2 = r2[0] + r2[1] + r2[2] + r2[3];
    float mean = s1 * (1.0f / Dm);
    float var = s2 * (1.0f / Dm) - mean * mean;
    float rstd = rsqrtf(var + 1e-5f);
    float4 wvv = *reinterpret_cast<const float4*>(&w[tid * 4]);
    float4 bv = *reinterpret_cast<const float4*>(&b[tid * 4]);
    ushort4 o;
    o.x = f2bf((v.x - mean) * rstd * wvv.x + bv.x);
    o.y = f2bf((v.y - mean) * rstd * wvv.y + bv.y);
    o.z = f2bf((v.z - mean) * rstd * wvv.z + bv.z);
    o.w = f2bf((v.w - mean) * rstd * wvv.w + bv.w);
    *reinterpret_cast<ushort4*>(&y[(size_t)row * Dm + tid * 4]) = o;
}

// ------------------------------------------------- fused per-layer weight transpose
__global__ __launch_bounds__(256)
void transpose_layer(const float* __restrict__ qw, const float* __restrict__ ow,
                     const float* __restrict__ uw, const float* __restrict__ dw,
                     unsigned short* __restrict__ wTq, unsigned short* __restrict__ wTo,
                     unsigned short* __restrict__ wTu, unsigned short* __restrict__ wTd) {
    __shared__ float t[32][33];
    int tb = blockIdx.x;
    const float* src; unsigned short* dst; int K, N, nx, base;
    if (tb < 3072)      { src = qw; dst = wTq; K = 1024; N = 3072; nx = 96;  base = 0; }
    else if (tb < 4096) { src = ow; dst = wTo; K = 1024; N = 1024; nx = 32;  base = 3072; }
    else if (tb < 8192) { src = uw; dst = wTu; K = 1024; N = 4096; nx = 128; base = 4096; }
    else                { src = dw; dst = wTd; K = 4096; N = 1024; nx = 32;  base = 8192; }
    int tt = tb - base;
    int n0 = (tt % nx) * 32, k0 = (tt / nx) * 32;
    int tid = threadIdx.x;
    int r = tid >> 3, c4 = (tid & 7) * 4;
    float4 v = *reinterpret_cast<const float4*>(&src[(size_t)(k0 + r) * N + n0 + c4]);
    t[r][c4] = v.x; t[r][c4 + 1] = v.y; t[r][c4 + 2] = v.z; t[r][c4 + 3] = v.w;
    __syncthreads();
    int nr = tid >> 3, kc = (tid & 7) * 4;
    ushort4 o;
    o.x = f2bf(t[kc][nr]);
    o.y = f2bf(t[kc + 1][nr]);
    o.z = f2bf(t[kc + 2][nr]);
    o.w = f2bf(t[kc + 3][nr]);
    *reinterpret_cast<ushort4*>(&dst[(size_t)(n0 + nr) * K + k0 + kc]) = o;
}

// ------------------------------------------------- f32 rows -> bf16 rows
__global__ __launch_bounds__(128)
void cvt_rows(unsigned short* __restrict__ dst, const float* __restrict__ src) {
    int row = blockIdx.x;
    int t = threadIdx.x;
    const float* s = src + (size_t)row * Dm + t * 8;
    float4 f0 = *reinterpret_cast<const float4*>(s);
    float4 f1 = *reinterpret_cast<const float4*>(s + 4);
    ushort4 o0, o1;
    o0.x = f2bf(f0.x); o0.y = f2bf(f0.y); o0.z = f2bf(f0.z); o0.w = f2bf(f0.w);
    o1.x = f2bf(f1.x); o1.y = f2bf(f1.y); o1.z = f2bf(f1.z); o1.w = f2bf(f1.w);
    unsigned short* d = dst + (size_t)row * Dm + t * 8;
    *reinterpret_cast<ushort4*>(d) = o0;
    *reinterpret_cast<ushort4*>(d + 4) = o1;
}

// ================================================================ 256x256 8-phase GEMM
// 512 thr = 8 waves (2M x 4N), per-wave 128x64. BK=64, 2 K-tiles/iter,
// half-tile slots [2 dbuf][2 half][128][64]; even tiles -> dbuf0, odd -> dbuf1.
// Per phase: {ds_read frags || stage 1 half-tile -> barrier -> 16 MFMA -> [vmcnt] -> barrier}.
// Counted vmcnt(4) at phase 3/7 ends.
// EPI 1: C bf16 = gelu(acc+bias). EPI 4: C f32 nontemporal + fused LSE partials.
template<int EPI, int GN>
__global__ __launch_bounds__(512, 1)
void gemm256p8(const unsigned short* __restrict__ A, const unsigned short* __restrict__ B,
               const float* __restrict__ bias, void* __restrict__ Cp,
               int Nv, int K, int ldc, int ncol,
               float* __restrict__ pm_out, float* __restrict__ ps_out) {
    __shared__ unsigned short AL[2][2][8192];   // [dbuf][half][128*64]
    __shared__ unsigned short BL[2][2][8192];
    const int tid = threadIdx.x;
    const int lane = tid & 63, w = tid >> 6;
    const int wr = w >> 2, wc = w & 3;
    const int g = lane >> 4, lr = lane & 15;

    // stripe-affinity XCD mapping
    const int gx = gridDim.x;
    const int ny = GN ? ((Nv + 255) >> 8) : (int)gridDim.y;
    int s = blockIdx.y * gx + blockIdx.x;
    int xcd = s & 7, t0b = s >> 3;
    int xblk = t0b % gx, istr = t0b / gx;
    int y = xcd + (istr << 3);
    if (GN && y >= ny) return;
    const int bm = xblk * 256;
    const int bn = y * 256;

    const int srow = tid >> 3;                    // 0..63
    const int gsrc = (tid & 7) ^ (srow & 7);
    size_t aofs[2][2], bofs[2][2];
#pragma unroll
    for (int h = 0; h < 2; ++h)
#pragma unroll
        for (int j = 0; j < 2; ++j) {
            int ra = bm + h * 128 + srow + j * 64;
            aofs[h][j] = (size_t)ra * K + gsrc * 8;
            int rb = bn + h * 128 + srow + j * 64;
            if (GN) rb = (rb < Nv) ? rb : (Nv - 1);
            bofs[h][j] = (size_t)rb * K + gsrc * 8;
        }
    const int dst0 = tid * 8, dst1 = tid * 8 + 4096;

    const int nt = K >> 6;     // 64-wide K-tiles (K % 128 == 0 assumed)
    const int ni = nt >> 1;

    f32x4 acc[8][4];
#pragma unroll
    for (int i = 0; i < 8; ++i)
#pragma unroll
        for (int j = 0; j < 4; ++j)
#pragma unroll
            for (int r = 0; r < 4; ++r) acc[i][j][r] = 0.f;

#define STG_A(d, h, kt) do { \
        gload16(A + aofs[h][0] + ((size_t)(kt) << 6), &AL[d][h][dst0]); \
        gload16(A + aofs[h][1] + ((size_t)(kt) << 6), &AL[d][h][dst1]); } while (0)
#define STG_B(d, h, kt) do { \
        gload16(B + bofs[h][0] + ((size_t)(kt) << 6), &BL[d][h][dst0]); \
        gload16(B + bofs[h][1] + ((size_t)(kt) << 6), &BL[d][h][dst1]); } while (0)

    // prologue: B(0),A(0) -> dbuf0 ; B(1) -> dbuf1  (A(1) staged in iter-0 p0/p1)
    STG_B(0, 0, 0); STG_B(0, 1, 0);
    STG_A(0, 0, 0); STG_A(0, 1, 0);
    STG_B(1, 0, 1); STG_B(1, 1, 1);
    asm volatile("s_waitcnt vmcnt(0)" ::: "memory");
    asm volatile("s_barrier" ::: "memory");

    const unsigned short* alw[2] = { &AL[0][wr][0], &AL[1][wr][0] };
    const unsigned short* blw[2] = { &BL[0][wc >> 1][0], &BL[1][wc >> 1][0] };
    const int rbB = (wc & 1) * 64;

    bfrag bfr[4][2], afr[2][2];

    for (int i = 0; i < ni; ++i) {
        const int t1 = 2 * i + 1;
        const int tp0 = 2 * i + 2, tp1 = 2 * i + 3;
        const bool pf = (tp0 < nt);
        // ===== phases 0-3: tile 2i (dbuf 0) =====
#pragma unroll
        for (int q = 0; q < 4; ++q) {
            if (q == 0) {
#pragma unroll
                for (int n_ = 0; n_ < 4; ++n_)
#pragma unroll
                    for (int ks = 0; ks < 2; ++ks) {
                        int row = rbB + n_ * 16 + lr;
                        int sg = (ks * 4 + g) ^ (row & 7);
                        bfr[n_][ks] = *reinterpret_cast<const bfrag*>(&blw[0][row * 64 + sg * 8]);
                    }
            }
#pragma unroll
            for (int m2 = 0; m2 < 2; ++m2)
#pragma unroll
                for (int ks = 0; ks < 2; ++ks) {
                    int row = q * 32 + m2 * 16 + lr;
                    int sg = (ks * 4 + g) ^ (row & 7);
                    afr[m2][ks] = *reinterpret_cast<const bfrag*>(&alw[0][row * 64 + sg * 8]);
                }
            if (q == 0)      { STG_A(1, 0, t1); }
            else if (q == 1) { STG_A(1, 1, t1); }
            else if (q == 2) { if (pf) STG_B(0, 0, tp0); }
            else             { if (pf) STG_B(0, 1, tp0); }
            asm volatile("s_barrier" ::: "memory");
            __builtin_amdgcn_s_setprio(1);
#pragma unroll
            for (int m2 = 0; m2 < 2; ++m2)
#pragma unroll
                for (int n_ = 0; n_ < 4; ++n_)
#pragma unroll
                    for (int ks = 0; ks < 2; ++ks)
                        acc[q * 2 + m2][n_] = __builtin_amdgcn_mfma_f32_16x16x32_bf16(
                            afr[m2][ks], bfr[n_][ks], acc[q * 2 + m2][n_], 0, 0, 0);
            __builtin_amdgcn_s_setprio(0);
            if (q == 3) {
                if (i + 1 < ni) asm volatile("s_waitcnt vmcnt(4)" ::: "memory");
                else            asm volatile("s_waitcnt vmcnt(0)" ::: "memory");
            }
            asm volatile("s_barrier" ::: "memory");
        }
        // ===== phases 4-7: tile 2i+1 (dbuf 1) =====
#pragma unroll
        for (int q = 0; q < 4; ++q) {
            if (q == 0) {
#pragma unroll
                for (int n_ = 0; n_ < 4; ++n_)
#pragma unroll
                    for (int ks = 0; ks < 2; ++ks) {
                        int row = rbB + n_ * 16 + lr;
                        int sg = (ks * 4 + g) ^ (row & 7);
                        bfr[n_][ks] = *reinterpret_cast<const bfrag*>(&blw[1][row * 64 + sg * 8]);
                    }
            }
#pragma unroll
            for (int m2 = 0; m2 < 2; ++m2)
#pragma unroll
                for (int ks = 0; ks < 2; ++ks) {
                    int row = q * 32 + m2 * 16 + lr;
                    int sg = (ks * 4 + g) ^ (row & 7);
                    afr[m2][ks] = *reinterpret_cast<const bfrag*>(&alw[1][row * 64 + sg * 8]);
                }
            if (q == 0)      { if (pf) STG_A(0, 0, tp0); }
            else if (q == 1) { if (pf) STG_A(0, 1, tp0); }
            else if (q == 2) { if (tp1 < nt) STG_B(1, 0, tp1); }
            else             { if (tp1 < nt) STG_B(1, 1, tp1); }
            asm volatile("s_barrier" ::: "memory");
            __builtin_amdgcn_s_setprio(1);
#pragma unroll
            for (int m2 = 0; m2 < 2; ++m2)
#pragma unroll
                for (int n_ = 0; n_ < 4; ++n_)
#pragma unroll
                    for (int ks = 0; ks < 2; ++ks)
                        acc[q * 2 + m2][n_] = __builtin_amdgcn_mfma_f32_16x16x32_bf16(
                            afr[m2][ks], bfr[n_][ks], acc[q * 2 + m2][n_], 0, 0, 0);
            __builtin_amdgcn_s_setprio(0);
            if (q == 3 && i + 1 < ni) asm volatile("s_waitcnt vmcnt(4)" ::: "memory");
            asm volatile("s_barrier" ::: "memory");
        }
    }
#undef STG_A
#undef STG_B

    unsigned short* Cb = (unsigned short*)Cp;
    float* Cf = (float*)Cp;

    if (EPI == 1) {
#pragma unroll
        for (int n_ = 0; n_ < 4; ++n_) {
            int col = bn + wc * 64 + n_ * 16 + lr;
            int gcol = ncol + col;
            float bi = bias[gcol];
#pragma unroll
            for (int mi = 0; mi < 8; ++mi) {
                int row0 = bm + wr * 128 + mi * 16 + g * 4;
#pragma unroll
                for (int r = 0; r < 4; ++r) {
                    int row = row0 + r;
                    float v = acc[mi][n_][r] + bi;
                    v = 0.5f * v * (1.0f + erff(v * 0.70710678118654752f));
                    Cb[(size_t)row * ldc + gcol] = f2bf(v);
                }
            }
        }
    } else {
        // fused logits store + per-row LSE partial over this block's 256 cols
        __syncthreads();
        float* lm = (float*)&AL[0][0][0];      // [256][4] row-max partials
        float* lsd = lm + 1024;                // [256][4] row-sumexp partials
        float bi4[4];
        int colv[4];
#pragma unroll
        for (int n_ = 0; n_ < 4; ++n_) {
            colv[n_] = bn + wc * 64 + n_ * 16 + lr;
            bi4[n_] = (colv[n_] < Nv) ? bias[ncol + colv[n_]] : 0.f;
        }
#pragma unroll
        for (int mi = 0; mi < 8; ++mi) {
#pragma unroll
            for (int r = 0; r < 4; ++r) {
                int row = bm + wr * 128 + mi * 16 + g * 4 + r;
                float vv[4];
                float ml = -3.0e38f, sl = 0.f;
#pragma unroll
                for (int n_ = 0; n_ < 4; ++n_) {
                    float v = acc[mi][n_][r] + bi4[n_];
                    vv[n_] = v;
                    if (colv[n_] < Nv) ml = fmaxf(ml, v);
                }
#pragma unroll
                for (int n_ = 0; n_ < 4; ++n_) {
                    if (colv[n_] < Nv) {
                        sl += __expf(vv[n_] - ml);
                        __builtin_nontemporal_store(
                            vv[n_], &Cf[(size_t)row * ldc + ncol + colv[n_]]);
                    }
                }
#pragma unroll
                for (int off = 1; off < 16; off <<= 1) {
                    float om = __shfl_xor(ml, off);
                    float os = __shfl_xor(sl, off);
                    float nm = fmaxf(ml, om);
                    sl = sl * __expf(ml - nm) + os * __expf(om - nm);
                    ml = nm;
                }
                if (lr == 0) {
                    int lrow = wr * 128 + mi * 16 + g * 4 + r;
                    lm[lrow * 4 + wc] = ml;
                    lsd[lrow * 4 + wc] = sl;
                }
            }
        }
        __syncthreads();
        if (tid < 256) {
            float m0 = lm[tid * 4 + 0], m1 = lm[tid * 4 + 1];
            float m2 = lm[tid * 4 + 2], m3 = lm[tid * 4 + 3];
            float M = fmaxf(fmaxf(m0, m1), fmaxf(m2, m3));
            float S = lsd[tid * 4 + 0] * __expf(m0 - M) + lsd[tid * 4 + 1] * __expf(m1 - M)
                    + lsd[tid * 4 + 2] * __expf(m2 - M) + lsd[tid * 4 + 3] * __expf(m3 - M);
            int row = bm + tid;
            int bno = bn >> 8;
            pm_out[(size_t)row * PLD + bno] = M;
            ps_out[(size_t)row * PLD + bno] = S;
        }
    }
}

// ================================================================ 128x128 pipelined GEMM
// 256 thr = 4 waves (2x2), per-wave 64x64. 64 KB LDS -> 2 blocks/CU.
// Merged phase + counted vmcnt ring. Stripe-affinity XCD mapping (gridDim.y % 8 == 0).
// EPI 0: bf16+bias. 2: f32 = R+acc+bias.
template<int EPI>
__global__ __launch_bounds__(256, 2)
void gemm128p(const unsigned short* __restrict__ A, const unsigned short* __restrict__ B,
              const float* __restrict__ bias, const float* __restrict__ R,
              void* __restrict__ Cp, int K, int ldc) {
    __shared__ unsigned short As[4][128 * 32];
    __shared__ unsigned short Bs[4][128 * 32];
    const int tid = threadIdx.x;
    const int lane = tid & 63, w = tid >> 6;
    const int wr = w >> 1, wc = w & 1;
    const int g = lane >> 4, lr = lane & 15;
    const int slotk = (lr >> 1) & 3;

    const int gx = gridDim.x;
    int s = blockIdx.y * gx + blockIdx.x;
    int xcd = s & 7, t0 = s >> 3;
    int xblk = t0 % gx, istr = t0 / gx;
    int y = xcd + (istr << 3);
    const int bm = xblk * 128;
    const int bn = y * 128;

    const int srow = lane >> 2;
    const int gsrc = (lane & 3) ^ ((lane >> 3) & 3);
    const int rA0 = (w * 2 + 0) * 16 + srow;
    const int rA1 = (w * 2 + 1) * 16 + srow;
    const size_t aoff0 = (size_t)(bm + rA0) * K + gsrc * 8;
    const size_t aoff1 = (size_t)(bm + rA1) * K + gsrc * 8;
    const size_t boff0 = (size_t)(bn + rA0) * K + gsrc * 8;
    const size_t boff1 = (size_t)(bn + rA1) * K + gsrc * 8;
    unsigned short* lA0 = &As[0][(w * 2 + 0) * 512];
    unsigned short* lA1 = &As[0][(w * 2 + 1) * 512];
    unsigned short* lB0 = &Bs[0][(w * 2 + 0) * 512];
    unsigned short* lB1 = &Bs[0][(w * 2 + 1) * 512];

    const int nt = K >> 5;

    f32x4 acc[4][4];
#pragma unroll
    for (int i = 0; i < 4; ++i)
#pragma unroll
        for (int j = 0; j < 4; ++j)
#pragma unroll
            for (int r = 0; r < 4; ++r) acc[i][j][r] = 0.f;

#pragma unroll
    for (int tp = 0; tp < 3; ++tp) {
        const int kp = tp << 5;
        gload16(A + aoff0 + kp, lA0 + tp * 4096);
        gload16(B + boff0 + kp, lB0 + tp * 4096);
        gload16(A + aoff1 + kp, lA1 + tp * 4096);
        gload16(B + boff1 + kp, lB1 + tp * 4096);
    }
    asm volatile("s_waitcnt vmcnt(8)" ::: "memory");
    asm volatile("s_barrier" ::: "memory");

    for (int t = 0; t < nt; ++t) {
        const int bt = t & 3;
        const unsigned short* as = As[bt];
        const unsigned short* bs = Bs[bt];
        const int pf = t + 3;
        const int kp = pf << 5;
        const int so = (pf & 3) * 4096;

        bfrag af[4], bfr[4];
#pragma unroll
        for (int i = 0; i < 4; ++i) {
            int ra = wr * 64 + i * 16 + lr;
            af[i] = *reinterpret_cast<const bfrag*>(&as[ra * 32 + ((g ^ slotk) * 8)]);
            int rb = wc * 64 + i * 16 + lr;
            bfr[i] = *reinterpret_cast<const bfrag*>(&bs[rb * 32 + ((g ^ slotk) * 8)]);
        }
        if (pf < nt) {
            gload16(A + aoff0 + kp, lA0 + so);
            gload16(B + boff0 + kp, lB0 + so);
            gload16(A + aoff1 + kp, lA1 + so);
            gload16(B + boff1 + kp, lB1 + so);
        }
        __builtin_amdgcn_s_setprio(1);
#pragma unroll
        for (int mi = 0; mi < 4; ++mi)
#pragma unroll
            for (int ni = 0; ni < 4; ++ni)
                acc[mi][ni] = __builtin_amdgcn_mfma_f32_16x16x32_bf16(
                    af[mi], bfr[ni], acc[mi][ni], 0, 0, 0);
        __builtin_amdgcn_s_setprio(0);
        if (t + 3 < nt)      asm volatile("s_waitcnt vmcnt(8)" ::: "memory");
        else if (t + 2 < nt) asm volatile("s_waitcnt vmcnt(4)" ::: "memory");
        else if (t + 1 < nt) asm volatile("s_waitcnt vmcnt(0)" ::: "memory");
        asm volatile("s_barrier" ::: "memory");
    }

    unsigned short* Cb = (unsigned short*)Cp;
    float* Cf = (float*)Cp;
#pragma unroll
    for (int ni = 0; ni < 4; ++ni) {
        int col = bn + wc * 64 + ni * 16 + lr;
        float bi = bias[col];
#pragma unroll
        for (int mi = 0; mi < 4; ++mi) {
            int row0 = bm + wr * 64 + mi * 16 + g * 4;
#pragma unroll
            for (int r = 0; r < 4; ++r) {
                int row = row0 + r;
                float v = acc[mi][ni][r] + bi;
                if (EPI == 0) {
                    Cb[(size_t)row * ldc + col] = f2bf(v);
                } else {
                    Cf[(size_t)row * ldc + col] = R[(size_t)row * ldc + col] + v;
                }
            }
        }
    }
}

// ---------------------------------------------------------------- MFMA attention
__global__ __launch_bounds__(256)
void attn_mfma(const unsigned short* __restrict__ qkv, unsigned short* __restrict__ ob) {
    const int bq = blockIdx.x;
    const int h = blockIdx.y;
    const int b = blockIdx.z;
    const int tid = threadIdx.x, lane = tid & 63, w = tid >> 6;
    const int g = lane >> 4, lr = lane & 15;
    const int qg0 = bq * 128 + w * 32;

    __shared__ unsigned short Kt[64 * 72];
    __shared__ unsigned short Vt[64 * 72];
    __shared__ unsigned short Pl[4][32 * 72];
    unsigned short* Plw = Pl[w];

    bfrag aq[2][2];
#pragma unroll
    for (int qs = 0; qs < 2; ++qs)
#pragma unroll
        for (int ks = 0; ks < 2; ++ks) {
            int row = qg0 + qs * 16 + lr;
            aq[qs][ks] = *reinterpret_cast<const bfrag*>(
                &qkv[(size_t)(b * Tt + row) * 3072 + h * 64 + ks * 32 + g * 8]);
        }

    float mrow[2][4], lrow[2][4], osc[2][4];
    f32x4 oacc[2][4];
#pragma unroll
    for (int qs = 0; qs < 2; ++qs)
#pragma unroll
        for (int r = 0; r < 4; ++r) { mrow[qs][r] = -3.0e38f; lrow[qs][r] = 0.f; }
#pragma unroll
    for (int qs = 0; qs < 2; ++qs)
#pragma unroll
        for (int dn = 0; dn < 4; ++dn)
#pragma unroll
            for (int r = 0; r < 4; ++r) oacc[qs][dn][r] = 0.f;

    const int ntile = 2 * bq + 2;
    for (int kt = 0; kt < ntile; ++kt) {
        {
            int row = tid >> 2, seg = tid & 3;
            const unsigned short* sk =
                &qkv[(size_t)(b * Tt + kt * 64 + row) * 3072 + Dm + h * 64 + seg * 16];
            bfrag kv0 = *(const bfrag*)sk;
            bfrag kv1 = *(const bfrag*)(sk + 8);
            *reinterpret_cast<bfrag*>(&Kt[row * 72 + seg * 16]) = kv0;
            *reinterpret_cast<bfrag*>(&Kt[row * 72 + seg * 16 + 8]) = kv1;
            const uint4* sv = reinterpret_cast<const uint4*>(
                &qkv[(size_t)(b * Tt + kt * 64 + row) * 3072 + 2 * Dm + h * 64 + seg * 16]);
            uint4 u0 = sv[0], u1 = sv[1];
            uint4 a, r0, r1;
            a.x = (seg & 1) ? u0.y : u0.x; a.y = (seg & 1) ? u0.z : u0.y;
            a.z = (seg & 1) ? u0.w : u0.z; a.w = (seg & 1) ? u0.x : u0.w;
            r0.x = (seg & 2) ? a.z : a.x; r0.y = (seg & 2) ? a.w : a.y;
            r0.z = (seg & 2) ? a.x : a.z; r0.w = (seg & 2) ? a.y : a.w;
            a.x = (seg & 1) ? u1.y : u1.x; a.y = (seg & 1) ? u1.z : u1.y;
            a.z = (seg & 1) ? u1.w : u1.z; a.w = (seg & 1) ? u1.x : u1.w;
            r1.x = (seg & 2) ? a.z : a.x; r1.y = (seg & 2) ? a.w : a.y;
            r1.z = (seg & 2) ? a.x : a.z; r1.w = (seg & 2) ? a.y : a.w;
            unsigned w0[4] = {r0.x, r0.y, r0.z, r0.w};
            unsigned w1[4] = {r1.x, r1.y, r1.z, r1.w};
#pragma unroll
            for (int i = 0; i < 8; ++i) {
                int j = (i + 2 * seg) & 7;
                unsigned ww = w0[i >> 1];
                unsigned short val = (i & 1) ? (unsigned short)(ww >> 16)
                                             : (unsigned short)(ww & 0xffff);
                Vt[(seg * 16 + j) * 72 + row] = val;
            }
#pragma unroll
            for (int i = 0; i < 8; ++i) {
                int j = (i + 2 * seg) & 7;
                unsigned ww = w1[i >> 1];
                unsigned short val = (i & 1) ? (unsigned short)(ww >> 16)
                                             : (unsigned short)(ww & 0xffff);
                Vt[(seg * 16 + 8 + j) * 72 + row] = val;
            }
        }
        __syncthreads();

        bool active = (kt * 64 <= qg0 + 31);
        if (active) {
            f32x4 s[2][4];
#pragma unroll
            for (int qs = 0; qs < 2; ++qs)
#pragma unroll
                for (int n = 0; n < 4; ++n)
#pragma unroll
                    for (int r = 0; r < 4; ++r) s[qs][n][r] = 0.f;
            bfrag bk[4][2];
#pragma unroll
            for (int n = 0; n < 4; ++n)
#pragma unroll
                for (int ks = 0; ks < 2; ++ks)
                    bk[n][ks] = *reinterpret_cast<const bfrag*>(
                        &Kt[(n * 16 + lr) * 72 + ks * 32 + g * 8]);
#pragma unroll
            for (int qs = 0; qs < 2; ++qs)
#pragma unroll
                for (int n = 0; n < 4; ++n)
#pragma unroll
                    for (int ks = 0; ks < 2; ++ks)
                        s[qs][n] = __builtin_amdgcn_mfma_f32_16x16x32_bf16(
                            aq[qs][ks], bk[n][ks], s[qs][n], 0, 0, 0);

            bool mayMask = (kt * 64 + 63 > qg0);
            float pv[2][4][4];
#pragma unroll
            for (int qs = 0; qs < 2; ++qs) {
#pragma unroll
                for (int r = 0; r < 4; ++r) {
                    int qrow = qg0 + qs * 16 + g * 4 + r;
                    float v[4];
#pragma unroll
                    for (int n = 0; n < 4; ++n) {
                        float sv = s[qs][n][r] * 0.125f;
                        if (mayMask && (kt * 64 + n * 16 + lr > qrow)) sv = -3.0e38f;
                        v[n] = sv;
                    }
                    float tmax = fmaxf(fmaxf(v[0], v[1]), fmaxf(v[2], v[3]));
                    tmax = fmaxf(tmax, __shfl_xor(tmax, 1));
                    tmax = fmaxf(tmax, __shfl_xor(tmax, 2));
                    tmax = fmaxf(tmax, __shfl_xor(tmax, 4));
                    tmax = fmaxf(tmax, __shfl_xor(tmax, 8));
                    float mold = mrow[qs][r];
                    float mnew = fmaxf(mold, tmax);
                    float scl = expf(mold - mnew);
                    float psum = 0.f;
#pragma unroll
                    for (int n = 0; n < 4; ++n) {
                        float p = expf(v[n] - mnew);
                        pv[qs][n][r] = p;
                        psum += p;
                    }
                    psum += __shfl_xor(psum, 1);
                    psum += __shfl_xor(psum, 2);
                    psum += __shfl_xor(psum, 4);
                    psum += __shfl_xor(psum, 8);
                    lrow[qs][r] = lrow[qs][r] * scl + psum;
                    mrow[qs][r] = mnew;
                    osc[qs][r] = scl;
                }
            }
#pragma unroll
            for (int qs = 0; qs < 2; ++qs)
#pragma unroll
                for (int dn = 0; dn < 4; ++dn)
#pragma unroll
                    for (int r = 0; r < 4; ++r) oacc[qs][dn][r] *= osc[qs][r];
#pragma unroll
            for (int qs = 0; qs < 2; ++qs)
#pragma unroll
                for (int n = 0; n < 4; ++n)
#pragma unroll
                    for (int r = 0; r < 4; ++r)
                        Plw[(qs * 16 + g * 4 + r) * 72 + n * 16 + lr] = f2bf(pv[qs][n][r]);
            asm volatile("s_waitcnt lgkmcnt(0)" ::: "memory");
            bfrag ap[2][2], bv[4][2];
#pragma unroll
            for (int qs = 0; qs < 2; ++qs)
#pragma unroll
                for (int ks = 0; ks < 2; ++ks)
                    ap[qs][ks] = *reinterpret_cast<const bfrag*>(
                        &Plw[(qs * 16 + lr) * 72 + ks * 32 + g * 8]);
#pragma unroll
            for (int dn = 0; dn < 4; ++dn)
#pragma unroll
                for (int ks = 0; ks < 2; ++ks)
                    bv[dn][ks] = *reinterpret_cast<const bfrag*>(
                        &Vt[(dn * 16 + lr) * 72 + ks * 32 + g * 8]);
#pragma unroll
            for (int qs = 0; qs < 2; ++qs)
#pragma unroll
                for (int dn = 0; dn < 4; ++dn)
#pragma unroll
                    for (int ks = 0; ks < 2; ++ks)
                        oacc[qs][dn] = __builtin_amdgcn_mfma_f32_16x16x32_bf16(
                            ap[qs][ks], bv[dn][ks], oacc[qs][dn], 0, 0, 0);
        }
        __syncthreads();
    }

#pragma unroll
    for (int qs = 0; qs < 2; ++qs)
#pragma unroll
        for (int r = 0; r < 4; ++r) {
            float rinv = 1.0f / lrow[qs][r];
            int qrow = qg0 + qs * 16 + g * 4 + r;
#pragma unroll
            for (int dn = 0; dn < 4; ++dn)
                ob[(size_t)(b * Tt + qrow) * Dm + h * 64 + dn * 16 + lr] =
                    f2bf(oacc[qs][dn][r] * rinv);
        }
}

// ---------------------------------------------------------------- loss combine
__global__ __launch_bounds__(64)
void loss_combine(float* __restrict__ nll, const float* __restrict__ pm,
                  const float* __restrict__ ps, const float* __restrict__ logits,
                  const int* __restrict__ targets, int nby) {
    const int row = blockIdx.x;
    const int lane = threadIdx.x;
    float m = -3.0e38f, s = 0.f;
    for (int j = lane; j < nby; j += 64) {
        float om = pm[(size_t)row * PLD + j];
        float os = ps[(size_t)row * PLD + j];
        float nm = fmaxf(m, om);
        s = s * __expf(m - nm) + os * __expf(om - nm);
        m = nm;
    }
#pragma unroll
    for (int off = 1; off < 64; off <<= 1) {
        float om = __shfl_xor(m, off);
        float os = __shfl_xor(s, off);
        float nm = fmaxf(m, om);
        s = s * __expf(m - nm) + os * __expf(om - nm);
        m = nm;
    }
    if (lane == 0) {
        float lse = m + __logf(s);
        nll[row] = lse - logits[(size_t)row * Vv + targets[row]];
    }
}

__global__ __launch_bounds__(256)
void loss_reduce_kernel(float* __restrict__ loss, const float* __restrict__ nll) {
    int tid = threadIdx.x;
    __shared__ float red[256];
    float s = 0.f;
    for (int j = tid; j < Mrows; j += 256) s += nll[j];
    red[tid] = s;
    __syncthreads();
    for (int st = 128; st > 0; st >>= 1) {
        if (tid < st) red[tid] += red[tid + st];
        __syncthreads();
    }
    if (tid == 0) *loss = red[0] * (1.0f / Mrows);
}

// ---------------------------------------------------------------- launch
extern "C" void kernel_launch(void* const* d_in, const int* in_sizes, int n_in,
                              void* d_out, int out_size, void* d_ws, size_t ws_size,
                              hipStream_t stream) {
    const int* idx = (const int*)d_in[0];
    const int* targets = (const int*)d_in[1];
    const float* wte = (const float*)d_in[2];
    const float* wpe = (const float*)d_in[3];
    const float* ln1_w = (const float*)d_in[4];
    const float* ln1_b = (const float*)d_in[5];
    const float* qkv_w = (const float*)d_in[6];
    const float* qkv_b = (const float*)d_in[7];
    const float* o_w = (const float*)d_in[8];
    const float* o_b = (const float*)d_in[9];
    const float* ln2_w = (const float*)d_in[10];
    const float* ln2_b = (const float*)d_in[11];
    const float* up_w = (const float*)d_in[12];
    const float* up_b = (const float*)d_in[13];
    const float* down_w = (const float*)d_in[14];
    const float* down_b = (const float*)d_in[15];
    const float* lnf_w = (const float*)d_in[16];
    const float* lnf_b = (const float*)d_in[17];
    const float* lm_b = (const float*)d_in[18];

    float* logits = (float*)d_out;
    char* ws = (char*)d_ws;
    const size_t MB = 1 << 20;
    float* x            = (float*)(ws);                       // 16 MB
    unsigned short* y   = (unsigned short*)(ws + 16 * MB);    // 8 MB
    unsigned short* qkv = (unsigned short*)(ws + 24 * MB);    // 24 MB
    unsigned short* ob  = (unsigned short*)(ws + 48 * MB);    // 8 MB
    unsigned short* up  = (unsigned short*)(ws + 56 * MB);    // 32 MB
    unsigned short* wTq = (unsigned short*)(ws + 88 * MB);    // 6.3 MB
    unsigned short* wTo = (unsigned short*)(ws + 96 * MB);    // 2.1 MB
    unsigned short* wTu = (unsigned short*)(ws + 100 * MB);   // 8.4 MB
    unsigned short* wTd = (unsigned short*)(ws + 112 * MB);   // 8.4 MB
    float* nll          = (float*)(ws + 127 * MB);            // 16 KB
    unsigned short* wbf = (unsigned short*)(ws + 24 * MB);    // lm phase (reuses qkv..)
    float* pmp          = (float*)(ws + 131 * MB);            // 3.3 MB
    float* psp          = (float*)(ws + 136 * MB);            // 3.3 MB

    embed_kernel<<<Mrows, 256, 0, stream>>>(x, wte, wpe, idx);

    for (int l = 0; l < Ll; ++l) {
        ln_kernel<<<Mrows, 256, 0, stream>>>(y, x, ln1_w + l * Dm, ln1_b + l * Dm);
        transpose_layer<<<12288, 256, 0, stream>>>(
            qkv_w + (size_t)l * Dm * 3 * Dm, o_w + (size_t)l * Dm * Dm,
            up_w + (size_t)l * Dm * 4 * Dm, down_w + (size_t)l * 4 * Dm * Dm,
            wTq, wTo, wTu, wTd);
        gemm128p<0><<<dim3(Mrows / 128, 3 * Dm / 128), 256, 0, stream>>>(
            y, wTq, qkv_b + (size_t)l * 3 * Dm, nullptr, qkv, Dm, 3 * Dm);
        attn_mfma<<<dim3(8, Hh, Bb), 256, 0, stream>>>(qkv, ob);
        gemm128p<2><<<dim3(Mrows / 128, Dm / 128), 256, 0, stream>>>(
            ob, wTo, o_b + (size_t)l * Dm, x, x, Dm, Dm);
        ln_kernel<<<Mrows, 256, 0, stream>>>(y, x, ln2_w + l * Dm, ln2_b + l * Dm);
        gemm256p8<1, 0><<<dim3(Mrows / 256, 4 * Dm / 256), 512, 0, stream>>>(
            y, wTu, up_b + (size_t)l * 4 * Dm, up, 4 * Dm, Dm, 4 * Dm, 0,
            nullptr, nullptr);
        gemm128p<2><<<dim3(Mrows / 128, Dm / 128), 256, 0, stream>>>(
            up, wTd, down_b + (size_t)l * Dm, x, x, 4 * Dm, Dm);
    }

    ln_kernel<<<Mrows, 256, 0, stream>>>(y, x, lnf_w, lnf_b);

    cvt_rows<<<Vv, 128, 0, stream>>>(wbf, wte);
    const int NBY = (Vv + 255) / 256;         // 197 valid stripes
    const int NBY_PAD = ((NBY + 7) / 8) * 8;  // 200 padded
    gemm256p8<4, 1><<<dim3(Mrows / 256, NBY_PAD), 512, 0, stream>>>(
        y, wbf, lm_b, logits, Vv, Dm, Vv, 0, pmp, psp);

    loss_combine<<<Mrows, 64, 0, stream>>>(nll, pmp, psp, logits, targets, NBY);
    loss_reduce_kernel<<<1, 256, 0, stream>>>(logits + (size_t)Mrows * Vv, nll);
}